// Round 1
// baseline (517.935 us; speedup 1.0000x reference)
//
#include <hip/hip_runtime.h>
#include <math.h>

// VectorQuantize: x [65536,64] f32, codebook [4096,64] f32.
// Outputs (flat f32 in d_out): quantized [N*C], idx [N] (as float), min_dists [N].
// Compute-bound: 34.4 GFLOP fp32, no fp32 MFMA on CDNA4 -> vector FMA path.

#define NROWS 65536
#define CDIM  64
#define KCB   4096
#define NWAVE 4
#define KCHUNK (KCB / NWAVE)   // 1024 codes per wave

// Prelude: c2[k] = ||codebook_k||^2  (1 MB read, negligible time).
__global__ __launch_bounds__(256) void c2_kernel(const float* __restrict__ cb,
                                                 float* __restrict__ c2) {
    int k = blockIdx.x * 256 + threadIdx.x;
    if (k >= KCB) return;
    const float* cp = cb + (size_t)k * CDIM;
    float s = 0.f;
    {
#pragma clang fp contract(off)
        for (int j = 0; j < CDIM; ++j) s += cp[j] * cp[j];
    }
    c2[k] = s;
}

// Main: block = 256 threads = 4 waves. Each wave scans a K/4 chunk for the
// block's 64 rows (one row per lane, x-row resident in 64 VGPRs).
// Codebook address is wave-uniform -> scalar load path, VALU stays pure FMA.
__global__ __launch_bounds__(256, 4) void vq_kernel(
    const float* __restrict__ x, const float* __restrict__ cb,
    const float* __restrict__ c2, float* __restrict__ outq,
    float* __restrict__ outidx, float* __restrict__ outd) {

    const int tid  = threadIdx.x;
    const int lane = tid & 63;
    const int wave = __builtin_amdgcn_readfirstlane(tid >> 6);  // force SGPR
    const int row  = blockIdx.x * 64 + lane;

    // Load this lane's x row into registers (16x float4, coalesced).
    float xr[CDIM];
    {
        const float4* xp = reinterpret_cast<const float4*>(x + (size_t)row * CDIM);
#pragma unroll
        for (int j = 0; j < CDIM / 4; ++j) {
            float4 v = xp[j];
            xr[4 * j + 0] = v.x; xr[4 * j + 1] = v.y;
            xr[4 * j + 2] = v.z; xr[4 * j + 3] = v.w;
        }
    }
    // x2 = sum(x*x): per-row constant (cancels in argmin; needed for dists).
    float x2 = 0.f;
    {
#pragma clang fp contract(off)
#pragma unroll
        for (int j = 0; j < CDIM; ++j) x2 += xr[j] * xr[j];
    }

    float bestd = __builtin_inff();
    int   besti = 0;
    const int k0 = wave * KCHUNK;

    for (int kk = 0; kk < KCHUNK; ++kk) {
        const int k = k0 + kk;   // wave-uniform
        const float4* cp4 = reinterpret_cast<const float4*>(cb + (size_t)k * CDIM);
        float da = 0.f, db = 0.f;   // two chains for ILP
#pragma unroll
        for (int j4 = 0; j4 < CDIM / 4; ++j4) {
            float4 cv = cp4[j4];
            da = fmaf(xr[4 * j4 + 0], cv.x, da);
            db = fmaf(xr[4 * j4 + 1], cv.y, db);
            da = fmaf(xr[4 * j4 + 2], cv.z, da);
            db = fmaf(xr[4 * j4 + 3], cv.w, db);
        }
        const float dot = da + db;
        // Reference order: (x2 - 2*dot) + c2   [fma(-2,dot,x2) == x2-2*dot exactly]
        const float d2 = fmaf(-2.f, dot, x2) + c2[k];
        if (d2 < bestd) { bestd = d2; besti = k; }   // strict < = first-occurrence
    }

    // Merge the 4 wave-chunk candidates per row via LDS.
    __shared__ float s_d[NWAVE][64];
    __shared__ int   s_i[NWAVE][64];
    s_d[wave][lane] = bestd;
    s_i[wave][lane] = besti;
    __syncthreads();

    if (tid < 64) {
        float bd = s_d[0][tid];
        int   bi = s_i[0][tid];
#pragma unroll
        for (int w = 1; w < NWAVE; ++w) {
            float d = s_d[w][tid];
            int   i2 = s_i[w][tid];
            if (d < bd || (d == bd && i2 < bi)) { bd = d; bi = i2; }
        }
        const int r = blockIdx.x * 64 + tid;
        outidx[r] = (float)bi;                    // harness reads d_out as f32
        outd[r]   = sqrtf(fmaxf(bd, 0.f));
        s_i[0][tid] = bi;                         // publish for gather phase
    }
    __syncthreads();

    // Gather quantized = codebook[idx] : 64 rows x 16 float4, 256 threads x 4.
    {
        const int r   = tid >> 2;
        const int seg = tid & 3;
        const int bi  = s_i[0][r];
        const float4* src = reinterpret_cast<const float4*>(cb + (size_t)bi * CDIM) + seg * 4;
        float4* dst = reinterpret_cast<float4*>(outq + (size_t)(blockIdx.x * 64 + r) * CDIM) + seg * 4;
#pragma unroll
        for (int t = 0; t < 4; ++t) dst[t] = src[t];
    }
}

extern "C" void kernel_launch(void* const* d_in, const int* in_sizes, int n_in,
                              void* d_out, int out_size, void* d_ws, size_t ws_size,
                              hipStream_t stream) {
    const float* x  = (const float*)d_in[0];
    const float* cb = (const float*)d_in[1];
    float* outq   = (float*)d_out;
    float* outidx = outq + (size_t)NROWS * CDIM;
    float* outd   = outidx + NROWS;
    float* c2     = (float*)d_ws;   // 16 KB scratch for ||c_k||^2

    c2_kernel<<<KCB / 256, 256, 0, stream>>>(cb, c2);
    vq_kernel<<<NROWS / 64, 256, 0, stream>>>(x, cb, c2, outq, outidx, outd);
}

// Round 2
// 204.561 us; speedup vs baseline: 2.5319x; 2.5319x over previous
//
#include <hip/hip_runtime.h>
#include <math.h>

// VectorQuantize via fp16-split MFMA emulation of fp32 GEMM.
// x [65536,64] f32, codebook [4096,64] f32.
// d_out (flat f32): quantized [N*64], idx [N] (as float), min_dists [N].
// dot(x,c) = hH + (hM+mH)*2^-12 + mM*2^-24 with h=fp16(x), m=fp16(4096*(x-h)).

#define NROWS 65536
#define CDIM  64
#define KCB   4096
#define RSCALE 4096.0f
#define S1 (1.0f/4096.0f)
#define S2 (1.0f/16777216.0f)

typedef _Float16 half8 __attribute__((ext_vector_type(8)));
typedef _Float16 half4 __attribute__((ext_vector_type(4)));
typedef float f32x4 __attribute__((ext_vector_type(4)));

#define MFMA16(A, B, C) __builtin_amdgcn_mfma_f32_16x16x32_f16(A, B, C, 0, 0, 0)

// ---- prep: codebook -> fp16 split (ch, cm) + c2h = 0.5*||c_k||^2 ----
__global__ __launch_bounds__(256) void prep_cb(const float* __restrict__ cb,
                                               _Float16* __restrict__ ch,
                                               _Float16* __restrict__ cm,
                                               float* __restrict__ c2h) {
    const int row = blockIdx.x * 16 + (threadIdx.x >> 4);
    const int j   = threadIdx.x & 15;
    const float4 v = *reinterpret_cast<const float4*>(cb + (size_t)row * CDIM + j * 4);
    float s;
    {
#pragma clang fp contract(off)
        s = v.x * v.x + v.y * v.y + v.z * v.z + v.w * v.w;
    }
    s += __shfl_xor(s, 1);
    s += __shfl_xor(s, 2);
    s += __shfl_xor(s, 4);
    s += __shfl_xor(s, 8);
    if (j == 0) c2h[row] = 0.5f * s;

    float e[4] = {v.x, v.y, v.z, v.w};
    half4 h, m;
#pragma unroll
    for (int t = 0; t < 4; ++t) {
        _Float16 hv = (_Float16)e[t];
        h[t] = hv;
        m[t] = (_Float16)((e[t] - (float)hv) * RSCALE);
    }
    *reinterpret_cast<half4*>(ch + (size_t)row * CDIM + j * 4) = h;
    *reinterpret_cast<half4*>(cm + (size_t)row * CDIM + j * 4) = m;
}

// ---- main: block = 4 waves. wave w: rows n0+(w&1)*64..+64, k-half (w>>1). ----
__global__ __launch_bounds__(256, 2) void vq_main(
    const float* __restrict__ x, const float* __restrict__ cb,
    const _Float16* __restrict__ ch, const _Float16* __restrict__ cm,
    const float* __restrict__ c2h,
    float* __restrict__ outq, float* __restrict__ outidx, float* __restrict__ outd) {

    const int tid  = threadIdx.x;
    const int lane = tid & 63;
    const int wv   = __builtin_amdgcn_readfirstlane(tid >> 6);
    const int rowgrp = wv & 1;
    const int khalf  = wv >> 1;
    const int lrow = lane & 15;          // A row / B col / D col
    const int lhi  = lane >> 4;          // k-slot group / D row group
    const int n0   = blockIdx.x * 128 + rowgrp * 64;
    const int kbase = khalf * 2048;

    __shared__ float sbd[2][128];
    __shared__ int   sbi[2][128];
    __shared__ float sx2[128];

    // A fragments (resident) + x2 partials
    half8 afh[4][2], afm[4][2];
    float x2p[4];
#pragma unroll
    for (int st = 0; st < 4; ++st) {
        float p = 0.f;
#pragma unroll
        for (int cs = 0; cs < 2; ++cs) {
            const float* xp = x + (size_t)(n0 + st * 16 + lrow) * CDIM + cs * 32 + lhi * 8;
            const float4 a = *reinterpret_cast<const float4*>(xp);
            const float4 b = *reinterpret_cast<const float4*>(xp + 4);
            float e[8] = {a.x, a.y, a.z, a.w, b.x, b.y, b.z, b.w};
#pragma unroll
            for (int jj = 0; jj < 8; ++jj) {
                _Float16 hv = (_Float16)e[jj];
                afh[st][cs][jj] = hv;
                afm[st][cs][jj] = (_Float16)((e[jj] - (float)hv) * RSCALE);
                p = fmaf(e[jj], e[jj], p);
            }
        }
        x2p[st] = p;
    }
    // x2: sum the 4 lhi-groups (lanes sharing lrow)
#pragma unroll
    for (int st = 0; st < 4; ++st) {
        x2p[st] += __shfl_xor(x2p[st], 16);
        x2p[st] += __shfl_xor(x2p[st], 32);
    }
    if (khalf == 0 && lhi == 0) {
#pragma unroll
        for (int st = 0; st < 4; ++st) sx2[rowgrp * 64 + st * 16 + lrow] = x2p[st];
    }

    float bd[4][4];
    int   bi[4][4];
#pragma unroll
    for (int st = 0; st < 4; ++st)
#pragma unroll
        for (int r = 0; r < 4; ++r) { bd[st][r] = 3.4e38f; bi[st][r] = 0; }

    const _Float16* phb = ch + (size_t)(kbase + lrow) * CDIM + lhi * 8;
    const _Float16* pmb = cm + (size_t)(kbase + lrow) * CDIM + lhi * 8;
    const float*    pc2 = c2h + kbase + lrow;

    for (int kt = 0; kt < 128; ++kt) {
        const half8 bh0 = *reinterpret_cast<const half8*>(phb + kt * 1024);
        const half8 bh1 = *reinterpret_cast<const half8*>(phb + kt * 1024 + 32);
        const half8 bm0 = *reinterpret_cast<const half8*>(pmb + kt * 1024);
        const half8 bm1 = *reinterpret_cast<const half8*>(pmb + kt * 1024 + 32);
        const float c2k = pc2[kt * 16];
        const int   kv  = kbase + kt * 16 + lrow;

        f32x4 a0[4], a1[4], a2[4];
#pragma unroll
        for (int st = 0; st < 4; ++st) { a0[st] = (f32x4)0.f; a1[st] = (f32x4)0.f; a2[st] = (f32x4)0.f; }
        // 12 independent MFMA chains (4 subtiles x 3 accumulators)
#pragma unroll
        for (int st = 0; st < 4; ++st) a0[st] = MFMA16(afh[st][0], bh0, a0[st]);
#pragma unroll
        for (int st = 0; st < 4; ++st) a0[st] = MFMA16(afh[st][1], bh1, a0[st]);
#pragma unroll
        for (int st = 0; st < 4; ++st) a1[st] = MFMA16(afm[st][0], bh0, a1[st]);
#pragma unroll
        for (int st = 0; st < 4; ++st) a1[st] = MFMA16(afm[st][1], bh1, a1[st]);
#pragma unroll
        for (int st = 0; st < 4; ++st) a1[st] = MFMA16(afh[st][0], bm0, a1[st]);
#pragma unroll
        for (int st = 0; st < 4; ++st) a1[st] = MFMA16(afh[st][1], bm1, a1[st]);
#pragma unroll
        for (int st = 0; st < 4; ++st) a2[st] = MFMA16(afm[st][0], bm0, a2[st]);
#pragma unroll
        for (int st = 0; st < 4; ++st) a2[st] = MFMA16(afm[st][1], bm1, a2[st]);

#pragma unroll
        for (int st = 0; st < 4; ++st) {
#pragma unroll
            for (int r = 0; r < 4; ++r) {
                float d = c2k - a0[st][r];          // c2/2 - S, argmin-equivalent
                d = fmaf(-S1, a1[st][r], d);
                d = fmaf(-S2, a2[st][r], d);
                const bool t = d < bd[st][r];       // strict < : first index wins
                bd[st][r] = t ? d : bd[st][r];
                bi[st][r] = t ? kv : bi[st][r];
            }
        }
    }

    // per-row k-reduce across the 16 lanes of each lhi-group
#pragma unroll
    for (int st = 0; st < 4; ++st) {
#pragma unroll
        for (int r = 0; r < 4; ++r) {
            float d = bd[st][r];
            int   i = bi[st][r];
#pragma unroll
            for (int mskk = 1; mskk <= 8; mskk <<= 1) {
                const float od = __shfl_xor(d, mskk);
                const int   oi = __shfl_xor(i, mskk);
                if (od < d || (od == d && oi < i)) { d = od; i = oi; }
            }
            if (lrow == 0) {
                const int rowl = rowgrp * 64 + st * 16 + lhi * 4 + r;
                sbd[khalf][rowl] = d;
                sbi[khalf][rowl] = i;
            }
        }
    }
    __syncthreads();

    if (tid < 128) {
        float d0 = sbd[0][tid];
        int   i0 = sbi[0][tid];
        const float d1 = sbd[1][tid];
        const int   i1 = sbi[1][tid];
        if (d1 < d0) { d0 = d1; i0 = i1; }   // k-half-1 indices are larger: strict <
        const int row = blockIdx.x * 128 + tid;
        outidx[row] = (float)i0;
        const float d2 = fmaf(2.f, d0, sx2[tid]);
        outd[row] = sqrtf(fmaxf(d2, 0.f));
        sbi[0][tid] = i0;                    // publish for gather
    }
    __syncthreads();

    // quantized = codebook[idx]: 2 threads/row x 8 float4
    {
        const int r   = tid >> 1;
        const int seg = tid & 1;
        const int b   = sbi[0][r];
        const float4* src = reinterpret_cast<const float4*>(cb + (size_t)b * CDIM) + seg * 8;
        float4* dst = reinterpret_cast<float4*>(outq + (size_t)(blockIdx.x * 128 + r) * CDIM) + seg * 8;
#pragma unroll
        for (int jj = 0; jj < 8; ++jj) dst[jj] = src[jj];
    }
}

extern "C" void kernel_launch(void* const* d_in, const int* in_sizes, int n_in,
                              void* d_out, int out_size, void* d_ws, size_t ws_size,
                              hipStream_t stream) {
    const float* x  = (const float*)d_in[0];
    const float* cb = (const float*)d_in[1];
    float* outq   = (float*)d_out;
    float* outidx = outq + (size_t)NROWS * CDIM;
    float* outd   = outidx + NROWS;

    _Float16* ch  = (_Float16*)d_ws;                 // 512 KB
    _Float16* cm  = ch + (size_t)KCB * CDIM;         // 512 KB
    float*    c2h = (float*)(cm + (size_t)KCB * CDIM); // 16 KB

    prep_cb<<<KCB / 16, 256, 0, stream>>>(cb, ch, cm, c2h);
    vq_main<<<NROWS / 128, 256, 0, stream>>>(x, cb, ch, cm, c2h, outq, outidx, outd);
}